// Round 5
// baseline (93.654 us; speedup 1.0000x reference)
//
#include <hip/hip_runtime.h>
#include <hip/hip_bf16.h>
#include <stdint.h>

typedef __attribute__((ext_vector_type(8))) short short8;
typedef __attribute__((ext_vector_type(8))) unsigned short ushort8;
typedef __attribute__((ext_vector_type(4))) float f32x4;
typedef __attribute__((ext_vector_type(4))) int int4v;

#define NHEAD 32
#define SEQ   2048
#define HN    128

static constexpr float INV_NORM = 0.08838834764831845f;  // 1/sqrt(128), folded into Q

__device__ __forceinline__ unsigned short f2bf(float f) {
  union { float f; unsigned u; } v; v.f = f;
  unsigned r = v.u + 0x7fffu + ((v.u >> 16) & 1u);   // RNE
  return (unsigned short)(r >> 16);
}

__device__ __forceinline__ f32x4 mfma16(short8 a, short8 b, f32x4 c) {
  return __builtin_amdgcn_mfma_f32_16x16x32_bf16(a, b, c, 0, 0, 0);
}

__device__ __forceinline__ void gl_lds16(const void* g, void* l) {
  __builtin_amdgcn_global_load_lds(
      (const __attribute__((address_space(1))) unsigned int*)g,
      (__attribute__((address_space(3))) unsigned int*)l, 16, 0, 0);
}

// ---- fused prep (unchanged, R3/R5-proven):
__global__ __launch_bounds__(256) void prep_kv(const float* __restrict__ K,
                                               const float* __restrict__ V,
                                               unsigned short* __restrict__ kswz,
                                               unsigned short* __restrict__ vT) {
  __shared__ unsigned short lds[128 * 136];
  int bid = blockIdx.x;
  int tid = threadIdx.x;
  if (bid < 4096) {
    int idx = bid * 256 + tid;     // chunk id: 32*2048*16
    int cl = idx & 15;
    int t  = (idx >> 4) & 2047;
    int bn = idx >> 15;
    const float4* src = (const float4*)(K + ((size_t)t * 32 + bn) * 128 + cl * 8);
    float4 a = src[0], b = src[1];
    ushort8 o;
    o[0]=f2bf(a.x); o[1]=f2bf(a.y); o[2]=f2bf(a.z); o[3]=f2bf(a.w);
    o[4]=f2bf(b.x); o[5]=f2bf(b.y); o[6]=f2bf(b.z); o[7]=f2bf(b.w);
    *(ushort8*)(kswz + ((size_t)bn * 2048 + t) * 128 + ((cl ^ (t & 7)) * 8)) = o;
  } else {
    int vb = bid - 4096;
    int bn = vb >> 4;
    int t0 = (vb & 15) << 7;
    int r = tid >> 1, h0 = (tid & 1) * 64;
    const float* src = V + ((size_t)(t0 + r) * 32 + bn) * 128 + h0;
#pragma unroll
    for (int j = 0; j < 8; ++j) {
      float4 a = *(const float4*)(src + j * 8);
      float4 b = *(const float4*)(src + j * 8 + 4);
      ushort8 o;
      o[0]=f2bf(a.x); o[1]=f2bf(a.y); o[2]=f2bf(a.z); o[3]=f2bf(a.w);
      o[4]=f2bf(b.x); o[5]=f2bf(b.y); o[6]=f2bf(b.z); o[7]=f2bf(b.w);
      *(ushort8*)&lds[r * 136 + h0 + j * 8] = o;
    }
    __syncthreads();
    int h = tid >> 1, ts = (tid & 1) * 64;
    unsigned short tmp[64];
#pragma unroll
    for (int j = 0; j < 64; ++j) {
      int p = j & 31;
      int tloc = ((p >> 3) & 3) * 4 + ((p >> 2) & 1) * 16 + (p & 3);
      tmp[j] = lds[(ts + (j & 32) + tloc) * 136 + h];
    }
    ushort8* dst = (ushort8*)(vT + ((size_t)bn * 128 + h) * 2048 + t0 + ts);
#pragma unroll
    for (int j = 0; j < 8; ++j) dst[j] = *(ushort8*)&tmp[j * 8];
  }
}

// ---- fragment/softmax helpers --------------------------------------------
__device__ __forceinline__ void read_kf(const char* kb, int l15, int hi,
                                        short8 (&kf)[2][4]) {
  int xr = (l15 & 7) << 4;      // (row&7)==(l15&7): nt offset is mult of 16
#pragma unroll
  for (int nt = 0; nt < 2; ++nt) {
    const char* krow = kb + (nt * 16 + l15) * 256;
#pragma unroll
    for (int kk = 0; kk < 4; ++kk)
      kf[nt][kk] = *(const short8*)(krow + (((kk * 4 + hi) * 16) ^ xr));
  }
}

__device__ __forceinline__ void read_vf(const char* vbh, int l15, int hi,
                                        short8 (&vf)[8]) {
#pragma unroll
  for (int ht = 0; ht < 8; ++ht)
    vf[ht] = *(const short8*)(vbh + (ht * 16 + l15) * 64 +
                              ((((l15 >> 1) + hi) & 3) * 16));
}

__device__ __forceinline__ short8 packp(const float (&e)[8], float& da) {
  da += ((e[0] + e[1]) + (e[2] + e[3])) + ((e[4] + e[5]) + (e[6] + e[7]));
  unsigned w0, w1, w2, w3;
  asm("v_cvt_pk_bf16_f32 %0, %1, %2" : "=v"(w0) : "v"(e[0]), "v"(e[1]));
  asm("v_cvt_pk_bf16_f32 %0, %1, %2" : "=v"(w1) : "v"(e[2]), "v"(e[3]));
  asm("v_cvt_pk_bf16_f32 %0, %1, %2" : "=v"(w2) : "v"(e[4]), "v"(e[5]));
  asm("v_cvt_pk_bf16_f32 %0, %1, %2" : "=v"(w3) : "v"(e[6]), "v"(e[7]));
  union { int4v u; short8 s; } pk;
  pk.u = (int4v){(int)w0, (int)w1, (int)w2, (int)w3};
  return pk.s;
}

// Q pre-scaled by 1/sqrt(128): probability = exp(S) directly.
__device__ __forceinline__ short8 softp_m(const f32x4 (&sv)[2], int t0h, int qbase,
                                          int l15, int hi, float& da) {
  float e[8];
#pragma unroll
  for (int nt = 0; nt < 2; ++nt)
#pragma unroll
    for (int i = 0; i < 4; ++i) {
      float x = __expf(sv[nt][i]);
      int kv = t0h + nt * 16 + hi * 4 + i;
      e[nt * 4 + i] = (kv <= qbase + l15) ? x : 0.0f;
    }
  return packp(e, da);
}

__device__ __forceinline__ short8 softp_u(const f32x4 (&sv)[2], float& da) {
  float e[8];
#pragma unroll
  for (int nt = 0; nt < 2; ++nt)
#pragma unroll
    for (int i = 0; i < 4; ++i)
      e[nt * 4 + i] = __expf(sv[nt][i]);
  return packp(e, da);
}

// ---- main: 1024 blocks x 512 threads (8 waves), ONE 64-row q-tile/block.
// kv-SPLIT inside the block: waves 0-3 = even 32-kv tiles, waves 4-7 = odd
// (no-max softmax => partials exactly additive; LDS combine at end).
// Critical path (qt=31 block) halves: 64 -> 32 serial tile iterations.
// LDS 64KB -> 2 blocks/CU = 16 waves/CU, SUSTAINED by replacement: grid
// 1024 blocks at 2 resident/CU, heavy blocks dispatched first (LPT).
// __launch_bounds__ cap = 256/w (R1/R3: w=4 -> 64 regs -> spill); w=2 ->
// 128-reg cap, per-wave state ~76 regs fits without spill.
__global__ __launch_bounds__(512, 2) void attn_main(const float* __restrict__ Q,
                                                    const unsigned short* __restrict__ kswz,
                                                    const unsigned short* __restrict__ vT,
                                                    float* __restrict__ out) {
  // LDS: K s0 2x8KB | K s1 2x8KB | V s0 2x8KB | V s1 2x8KB = 65536
  __shared__ char smem[65536];
  int tid = threadIdx.x;
  int lane = tid & 63;
  int w8 = tid >> 6;                    // 0..7
  int w = w8 & 3;                       // row-group wave (16 q-rows)
  int sid = w8 >> 2;                    // kv stream: 0=even tiles, 1=odd
  int l15 = lane & 15;
  int hi = lane >> 4;

  int bid = blockIdx.x;
  int bn = bid & 31;                    // head -> XCD bid%8 = bn%8 (stable)
  int z = bid >> 5;                     // [0,32)
  int qt = 31 - z;                      // heavy (long) blocks first: LPT
  int qb = qt * 64 + w * 16;            // this wave's 16 q-rows
  int nIt = qt + 1;                     // per-stream 32-kv tiles

  // Q B-fragments, PRE-SCALED by 1/sqrt(128): softmax is exp(S) direct.
  // (waves w and w+4 load the same rows; 2nd read is L1-hot, same CU)
  short8 qf[4];
  {
    const float* qrow = Q + ((size_t)(qb + l15) * 32 + bn) * 128;
#pragma unroll
    for (int kk = 0; kk < 4; ++kk) {
      float4 a = *(const float4*)(qrow + kk * 32 + hi * 8);
      float4 b = *(const float4*)(qrow + kk * 32 + hi * 8 + 4);
      short8 o;
      o[0]=(short)f2bf(a.x*INV_NORM); o[1]=(short)f2bf(a.y*INV_NORM);
      o[2]=(short)f2bf(a.z*INV_NORM); o[3]=(short)f2bf(a.w*INV_NORM);
      o[4]=(short)f2bf(b.x*INV_NORM); o[5]=(short)f2bf(b.y*INV_NORM);
      o[6]=(short)f2bf(b.z*INV_NORM); o[7]=(short)f2bf(b.w*INV_NORM);
      qf[kk] = o;
    }
  }

  f32x4 zz = {0.f, 0.f, 0.f, 0.f};
  f32x4 acc[8];
#pragma unroll
  for (int ht = 0; ht < 8; ++ht) acc[ht] = zz;
  float dacc = 0.f;

  const char* kg = (const char*)(kswz + (size_t)bn * 2048 * 128);
  const char* vg = (const char*)(vT + (size_t)bn * 128 * 2048);

  char* kbase = smem + sid * 16384;           // this stream's two K bufs
  char* vbase = smem + 32768 + sid * 16384;   // this stream's two V bufs

  auto stage = [&](int buf, int t) {  // stage 32-kv tile t (4 gl_lds per lane)
    const char* ksrc = kg + (size_t)t * 8192;
    char* kl = kbase + buf * 8192;
    int c = w * 64 + lane;            // 0..255 (stream's 4 waves)
#pragma unroll
    for (int rr = 0; rr < 2; ++rr)
      gl_lds16(ksrc + (size_t)(c + rr * 256) * 16, kl + (c + rr * 256) * 16);
    char* vl = vbase + buf * 8192;
#pragma unroll
    for (int rr = 0; rr < 2; ++rr) {
      int c2 = c + rr * 256;          // 0..511 within tile
      int h = c2 >> 2, sp = c2 & 3;
      int sl = (sp - (h >> 1)) & 3;
      gl_lds16(vg + (size_t)h * 4096 + (size_t)t * 64 + sl * 16,
               vl + c2 * 16);
    }
  };

  // drain Q loads so in-loop vmcnt sees ONLY stage loads
  asm volatile("s_waitcnt vmcnt(0)" ::: "memory");
  stage(0, sid);

  int cur = 0;
  for (int it = 0; it < nIt; ++it) {
    int t = it * 2 + sid;
    int t0h = t * 32;
    asm volatile("s_waitcnt vmcnt(0)" ::: "memory");   // my stage landed
    __builtin_amdgcn_s_barrier();                      // all waves' stage done

    const char* kb = kbase + cur * 8192;
    const char* vbh = vbase + cur * 8192;
    bool act = (t0h <= qb + 15);

    // K fragments first: ds latency hides under stage-issue
    short8 kf[2][4];
    if (act) read_kf(kb, l15, hi, kf);
    if (it + 1 < nIt) stage(cur ^ 1, t + 2);           // prefetch next tile

    if (act) {
      // QK^T (swapped): lane holds S^T[kv = 4hi+i (+16nt)][q = l15]
      f32x4 sv[2] = {zz, zz};
      __builtin_amdgcn_s_setprio(1);
#pragma unroll
      for (int nt = 0; nt < 2; ++nt)
#pragma unroll
        for (int kk = 0; kk < 4; ++kk)
          sv[nt] = mfma16(kf[nt][kk], qf[kk], sv[nt]);
      __builtin_amdgcn_s_setprio(0);
      // V fragment reads; latency hides under softmax
      short8 vf[8];
      read_vf(vbh, l15, hi, vf);
      bool mask = (t0h + 31 > qb);
      short8 p = mask ? softp_m(sv, t0h, qb, l15, hi, dacc)
                      : softp_u(sv, dacc);
      // PV (V rows pre-permuted to match P k-slot order)
      __builtin_amdgcn_s_setprio(1);
#pragma unroll
      for (int ht = 0; ht < 8; ++ht)
        acc[ht] = mfma16(p, vf[ht], acc[ht]);
      __builtin_amdgcn_s_setprio(0);
    }
    cur ^= 1;
  }

  // ---- combine kv-streams (partials exactly additive: no-max softmax)
  __syncthreads();                      // all LDS tile reads done
  int sl = w * 64 + lane;               // 0..255 within stream
  float* dsm = (float*)smem;
  if (sid == 1) dsm[sl] = dacc;
  __syncthreads();
  if (sid == 0) dacc += dsm[sl];
  __syncthreads();
  f32x4* accsm = (f32x4*)smem;          // [ht][256 lanes] = 32KB
  if (sid == 1) {
#pragma unroll
    for (int ht = 0; ht < 8; ++ht) accsm[ht * 256 + sl] = acc[ht];
  }
  __syncthreads();
  if (sid == 1) return;
#pragma unroll
  for (int ht = 0; ht < 8; ++ht) {
    f32x4 o = accsm[ht * 256 + sl];
    acc[ht][0] += o[0]; acc[ht][1] += o[1];
    acc[ht][2] += o[2]; acc[ht][3] += o[3];
  }

  // denominator: reduce partials across hi (lanes l15 + 16*hi)
  {
    float d = dacc;
    d += __shfl_xor(d, 16);
    d += __shfl_xor(d, 32);
    dacc = d;                        // function of l15 only
  }
  float* dn = out + 8388608;
  if (hi == 0) dn[(size_t)bn * 2048 + qb + l15] = dacc;

  // per-output-row inverse denominators via lane broadcast
  float inv[4];
#pragma unroll
  for (int i = 0; i < 4; ++i)
    inv[i] = __builtin_amdgcn_rcpf(__shfl(dacc, hi * 4 + i));

  // ctx: out[s*4096 + bn*128 + h]; lane holds O[q = qb+4hi+i][h = 16ht+l15]
#pragma unroll
  for (int i = 0; i < 4; ++i) {
    float* orow = out + (size_t)(qb + hi * 4 + i) * 4096 + bn * 128 + l15;
#pragma unroll
    for (int ht = 0; ht < 8; ++ht)
      orow[ht * 16] = acc[ht][i] * inv[i];
  }
}

extern "C" void kernel_launch(void* const* d_in, const int* in_sizes, int n_in,
                              void* d_out, int out_size, void* d_ws, size_t ws_size,
                              hipStream_t stream) {
  const float* Q = (const float*)d_in[0];
  const float* K = (const float*)d_in[1];
  const float* V = (const float*)d_in[2];
  float* out = (float*)d_out;

  unsigned short* kswz = (unsigned short*)d_ws;
  unsigned short* vT   = kswz + (size_t)NHEAD * SEQ * HN;

  prep_kv<<<4608, 256, 0, stream>>>(K, V, kswz, vT);
  attn_main<<<1024, 512, 0, stream>>>(Q, kswz, vT, out);
}

// Round 6
// 85.431 us; speedup vs baseline: 1.0963x; 1.0963x over previous
//
#include <hip/hip_runtime.h>
#include <hip/hip_bf16.h>
#include <stdint.h>

typedef __attribute__((ext_vector_type(8))) short short8;
typedef __attribute__((ext_vector_type(8))) unsigned short ushort8;
typedef __attribute__((ext_vector_type(4))) float f32x4;
typedef __attribute__((ext_vector_type(4))) int int4v;

#define NHEAD 32
#define SEQ   2048
#define HN    128

static constexpr float INV_NORM = 0.08838834764831845f;  // 1/sqrt(128), folded into Q

__device__ __forceinline__ unsigned short f2bf(float f) {
  union { float f; unsigned u; } v; v.f = f;
  unsigned r = v.u + 0x7fffu + ((v.u >> 16) & 1u);   // RNE
  return (unsigned short)(r >> 16);
}

__device__ __forceinline__ f32x4 mfma16(short8 a, short8 b, f32x4 c) {
  return __builtin_amdgcn_mfma_f32_16x16x32_bf16(a, b, c, 0, 0, 0);
}

__device__ __forceinline__ void gl_lds16(const void* g, void* l) {
  __builtin_amdgcn_global_load_lds(
      (const __attribute__((address_space(1))) unsigned int*)g,
      (__attribute__((address_space(3))) unsigned int*)l, 16, 0, 0);
}

// ---- fused prep (unchanged, R3/R5-proven):
__global__ __launch_bounds__(256) void prep_kv(const float* __restrict__ K,
                                               const float* __restrict__ V,
                                               unsigned short* __restrict__ kswz,
                                               unsigned short* __restrict__ vT) {
  __shared__ unsigned short lds[128 * 136];
  int bid = blockIdx.x;
  int tid = threadIdx.x;
  if (bid < 4096) {
    int idx = bid * 256 + tid;     // chunk id: 32*2048*16
    int cl = idx & 15;
    int t  = (idx >> 4) & 2047;
    int bn = idx >> 15;
    const float4* src = (const float4*)(K + ((size_t)t * 32 + bn) * 128 + cl * 8);
    float4 a = src[0], b = src[1];
    ushort8 o;
    o[0]=f2bf(a.x); o[1]=f2bf(a.y); o[2]=f2bf(a.z); o[3]=f2bf(a.w);
    o[4]=f2bf(b.x); o[5]=f2bf(b.y); o[6]=f2bf(b.z); o[7]=f2bf(b.w);
    *(ushort8*)(kswz + ((size_t)bn * 2048 + t) * 128 + ((cl ^ (t & 7)) * 8)) = o;
  } else {
    int vb = bid - 4096;
    int bn = vb >> 4;
    int t0 = (vb & 15) << 7;
    int r = tid >> 1, h0 = (tid & 1) * 64;
    const float* src = V + ((size_t)(t0 + r) * 32 + bn) * 128 + h0;
#pragma unroll
    for (int j = 0; j < 8; ++j) {
      float4 a = *(const float4*)(src + j * 8);
      float4 b = *(const float4*)(src + j * 8 + 4);
      ushort8 o;
      o[0]=f2bf(a.x); o[1]=f2bf(a.y); o[2]=f2bf(a.z); o[3]=f2bf(a.w);
      o[4]=f2bf(b.x); o[5]=f2bf(b.y); o[6]=f2bf(b.z); o[7]=f2bf(b.w);
      *(ushort8*)&lds[r * 136 + h0 + j * 8] = o;
    }
    __syncthreads();
    int h = tid >> 1, ts = (tid & 1) * 64;
    unsigned short tmp[64];
#pragma unroll
    for (int j = 0; j < 64; ++j) {
      int p = j & 31;
      int tloc = ((p >> 3) & 3) * 4 + ((p >> 2) & 1) * 16 + (p & 3);
      tmp[j] = lds[(ts + (j & 32) + tloc) * 136 + h];
    }
    ushort8* dst = (ushort8*)(vT + ((size_t)bn * 128 + h) * 2048 + t0 + ts);
#pragma unroll
    for (int j = 0; j < 8; ++j) dst[j] = *(ushort8*)&tmp[j * 8];
  }
}

// ---- fragment/softmax helpers --------------------------------------------
__device__ __forceinline__ void read_kf(const char* kb, int base, int l15, int hi,
                                        short8 (&kf)[2][4]) {
  int xr = (l15 & 7) << 4;   // rows base+nt*16+l15: (row&7)==(l15&7), xr invariant
#pragma unroll
  for (int nt = 0; nt < 2; ++nt) {
    const char* krow = kb + (base + nt * 16 + l15) * 256;
#pragma unroll
    for (int kk = 0; kk < 4; ++kk)
      kf[nt][kk] = *(const short8*)(krow + (((kk * 4 + hi) * 16) ^ xr));
  }
}

__device__ __forceinline__ void read_vf(const char* vbh, int l15, int hi,
                                        short8 (&vf)[8]) {
#pragma unroll
  for (int ht = 0; ht < 8; ++ht)
    vf[ht] = *(const short8*)(vbh + (ht * 16 + l15) * 64 +
                              ((((l15 >> 1) + hi) & 3) * 16));
}

__device__ __forceinline__ short8 packp(const float (&e)[8], float& da) {
  da += ((e[0] + e[1]) + (e[2] + e[3])) + ((e[4] + e[5]) + (e[6] + e[7]));
  unsigned w0, w1, w2, w3;
  asm("v_cvt_pk_bf16_f32 %0, %1, %2" : "=v"(w0) : "v"(e[0]), "v"(e[1]));
  asm("v_cvt_pk_bf16_f32 %0, %1, %2" : "=v"(w1) : "v"(e[2]), "v"(e[3]));
  asm("v_cvt_pk_bf16_f32 %0, %1, %2" : "=v"(w2) : "v"(e[4]), "v"(e[5]));
  asm("v_cvt_pk_bf16_f32 %0, %1, %2" : "=v"(w3) : "v"(e[6]), "v"(e[7]));
  union { int4v u; short8 s; } pk;
  pk.u = (int4v){(int)w0, (int)w1, (int)w2, (int)w3};
  return pk.s;
}

// Q pre-scaled by 1/sqrt(128): probability = exp(S) directly.
__device__ __forceinline__ short8 softp_m(const f32x4 (&sv)[2], int t0h, int qbase,
                                          int l15, int hi, float& da) {
  float e[8];
#pragma unroll
  for (int nt = 0; nt < 2; ++nt)
#pragma unroll
    for (int i = 0; i < 4; ++i) {
      float x = __expf(sv[nt][i]);
      int kv = t0h + nt * 16 + hi * 4 + i;
      e[nt * 4 + i] = (kv <= qbase + l15) ? x : 0.0f;
    }
  return packp(e, da);
}

__device__ __forceinline__ short8 softp_u(const f32x4 (&sv)[2], float& da) {
  float e[8];
#pragma unroll
  for (int nt = 0; nt < 2; ++nt)
#pragma unroll
    for (int i = 0; i < 4; ++i)
      e[nt * 4 + i] = __expf(sv[nt][i]);
  return packp(e, da);
}

// One 32-kv half-tile for TWO 16-row q-subtiles sharing the K-fragment
// reads (the LDS-amortization lever).  q0 = rows qb0..qb0+15,
// q1 = rows qb0+16..qb0+31.  Numerics identical to R0 path.
__device__ __forceinline__ void half_tile(
    const char* kb, const char* vbh, int halfbase, int t0h, int q0, int q1,
    int l15, int hi, const short8 (&qf)[2][4],
    f32x4 (&acc)[2][8], float (&dacc)[2]) {
  f32x4 zz = {0.f, 0.f, 0.f, 0.f};
  short8 kf[2][4];
  read_kf(kb, halfbase, l15, hi, kf);
  // QK^T (swapped): lane holds S^T[kv = 4hi+i (+16nt)][q = l15]
  f32x4 s0[2] = {zz, zz}, s1[2] = {zz, zz};
  __builtin_amdgcn_s_setprio(1);
#pragma unroll
  for (int nt = 0; nt < 2; ++nt)
#pragma unroll
    for (int kk = 0; kk < 4; ++kk) {
      s0[nt] = mfma16(kf[nt][kk], qf[0][kk], s0[nt]);
      s1[nt] = mfma16(kf[nt][kk], qf[1][kk], s1[nt]);
    }
  __builtin_amdgcn_s_setprio(0);
  // V fragment reads; latency hides under softmax
  short8 vf[8];
  read_vf(vbh, l15, hi, vf);
  // Diagonal tile needs masking (both subtiles); interior tiles don't.
  bool m0 = (t0h + 31 > q0);
  short8 p0 = m0 ? softp_m(s0, t0h, q0, l15, hi, dacc[0]) : softp_u(s0, dacc[0]);
  bool m1 = (t0h + 31 > q1);
  short8 p1 = m1 ? softp_m(s1, t0h, q1, l15, hi, dacc[1]) : softp_u(s1, dacc[1]);
  // PV (V rows pre-permuted to match P k-slot order)
  __builtin_amdgcn_s_setprio(1);
#pragma unroll
  for (int ht = 0; ht < 8; ++ht) {
    acc[0][ht] = mfma16(p0, vf[ht], acc[0][ht]);
    acc[1][ht] = mfma16(p1, vf[ht], acc[1][ht]);
  }
  __builtin_amdgcn_s_setprio(0);
}

// ---- main: 512 blocks x 256 threads, block = ONE 128-row q-tile,
// 4 waves x 32 CONTIGUOUS q-rows (two 16-row subtiles sharing K-frag
// reads -> LDS read traffic per unit MFMA work HALVES vs 16-row waves;
// model: R4 was ~97% LDS-port-bound).  KVB=64 double-buffered, 64KB LDS,
// 2 blocks/CU, one barrier per 64 kv.
// Balance: qt = (z<8)? 15-z : z-8 -> co-resident pair {z, z+8} sums to
// 34 64-kv iterations (uniform per-CU LDS traffic); heavy first (LPT).
// __launch_bounds__(256,2): 128-reg cap (R1/R3: min-waves w caps at 256/w).
__global__ __launch_bounds__(256, 2) void attn_main(const float* __restrict__ Q,
                                                    const unsigned short* __restrict__ kswz,
                                                    const unsigned short* __restrict__ vT,
                                                    float* __restrict__ out) {
  // LDS: K 2x16KB | V 2x16KB (each V buf = two 8KB halves) = 65536
  __shared__ char smem[65536];
  int tid = threadIdx.x;
  int lane = tid & 63;
  int w = tid >> 6;
  int l15 = lane & 15;
  int hi = lane >> 4;

  int bid = blockIdx.x;
  int bn = bid & 31;                    // head -> XCD bid%8 = bn%8 (stable)
  int z = bid >> 5;                     // [0,16)
  int qt = (z < 8) ? (15 - z) : (z - 8);
  int qb0 = qt * 128 + w * 32;          // subtile0 base (rows qb0..qb0+15)
  int qb1 = qb0 + 16;                   // subtile1 base (rows +16..+31)
  int ntile = 2 * qt + 2;               // 64-kv iterations

  // Q B-fragments, PRE-SCALED by 1/sqrt(128): softmax is exp(S) direct.
  short8 qf[2][4];
#pragma unroll
  for (int qs = 0; qs < 2; ++qs) {
    int qbase = qs ? qb1 : qb0;
    const float* qrow = Q + ((size_t)(qbase + l15) * 32 + bn) * 128;
#pragma unroll
    for (int kk = 0; kk < 4; ++kk) {
      float4 a = *(const float4*)(qrow + kk * 32 + hi * 8);
      float4 b = *(const float4*)(qrow + kk * 32 + hi * 8 + 4);
      short8 o;
      o[0]=(short)f2bf(a.x*INV_NORM); o[1]=(short)f2bf(a.y*INV_NORM);
      o[2]=(short)f2bf(a.z*INV_NORM); o[3]=(short)f2bf(a.w*INV_NORM);
      o[4]=(short)f2bf(b.x*INV_NORM); o[5]=(short)f2bf(b.y*INV_NORM);
      o[6]=(short)f2bf(b.z*INV_NORM); o[7]=(short)f2bf(b.w*INV_NORM);
      qf[qs][kk] = o;
    }
  }

  f32x4 zz = {0.f, 0.f, 0.f, 0.f};
  f32x4 acc[2][8];
#pragma unroll
  for (int qs = 0; qs < 2; ++qs)
#pragma unroll
    for (int ht = 0; ht < 8; ++ht) acc[qs][ht] = zz;
  float dacc[2] = {0.f, 0.f};

  const char* kg = (const char*)(kswz + (size_t)bn * 2048 * 128);
  const char* vg = (const char*)(vT + (size_t)bn * 128 * 2048);

  auto stage = [&](int buf, int t0) {  // 8 global_load_lds per lane (16KB K + 16KB V)
    const char* ksrc = kg + (size_t)t0 * 256;
    char* kl = smem + buf * 16384;
    int c = w * 64 + lane;
#pragma unroll
    for (int rr = 0; rr < 4; ++rr)
      gl_lds16(ksrc + (size_t)(c + rr * 256) * 16, kl + (c + rr * 256) * 16);
    char* vl = smem + 32768 + buf * 16384;
#pragma unroll
    for (int s = 0; s < 2; ++s)
#pragma unroll
      for (int rr = 0; rr < 2; ++rr) {
        int c2 = c + rr * 256;         // 0..511 within half
        int h = c2 >> 2, sp = c2 & 3;
        int sl = (sp - (h >> 1)) & 3;
        gl_lds16(vg + (size_t)h * 4096 + (t0 + s * 32) * 2 + sl * 16,
                 vl + s * 8192 + c2 * 16);
      }
  };

  // drain Q loads so in-loop vmcnt sees ONLY stage loads
  asm volatile("s_waitcnt vmcnt(0)" ::: "memory");
  stage(0, 0);

  int cur = 0;
  for (int it = 0; it < ntile; ++it) {
    int t0 = it * 64;
    asm volatile("s_waitcnt vmcnt(0)" ::: "memory");   // stage(it) landed
    __builtin_amdgcn_s_barrier();                      // all waves' stage done
    if (it + 1 < ntile) stage(cur ^ 1, t0 + 64);       // prefetch next tile

    const char* kb = smem + cur * 16384;
    const char* vb = smem + 32768 + cur * 16384;
#pragma unroll
    for (int half = 0; half < 2; ++half) {
      int t0h = t0 + half * 32;
      // 32-kv granularity: both subtiles active iff t0h <= qb0
      if (t0h <= qb0)
        half_tile(kb, vb + half * 8192, half * 32, t0h, qb0, qb1,
                  l15, hi, qf, acc, dacc);
    }
    cur ^= 1;
  }

  // denominator: reduce partials across hi (lanes l15 + 16*hi)
#pragma unroll
  for (int qs = 0; qs < 2; ++qs) {
    float d = dacc[qs];
    d += __shfl_xor(d, 16);
    d += __shfl_xor(d, 32);
    dacc[qs] = d;                        // function of l15 only
  }
  float* dn = out + 8388608;
  if (hi == 0) {
    dn[(size_t)bn * 2048 + qb0 + l15] = dacc[0];
    dn[(size_t)bn * 2048 + qb1 + l15] = dacc[1];
  }
  // per-output-row inverse denominators via lane broadcast
  float inv0[4], inv1[4];
#pragma unroll
  for (int i = 0; i < 4; ++i) {
    inv0[i] = __builtin_amdgcn_rcpf(__shfl(dacc[0], hi * 4 + i));
    inv1[i] = __builtin_amdgcn_rcpf(__shfl(dacc[1], hi * 4 + i));
  }

  // ctx: out[s*4096 + bn*128 + h]; lane holds O[q = base+4hi+i][h = 16ht+l15]
#pragma unroll
  for (int qs = 0; qs < 2; ++qs) {
    int qbase = qs ? qb1 : qb0;
#pragma unroll
    for (int i = 0; i < 4; ++i) {
      float inv = qs ? inv1[i] : inv0[i];
      float* orow = out + (size_t)(qbase + hi * 4 + i) * 4096 + bn * 128 + l15;
#pragma unroll
      for (int ht = 0; ht < 8; ++ht)
        orow[ht * 16] = acc[qs][ht][i] * inv;
    }
  }
}

extern "C" void kernel_launch(void* const* d_in, const int* in_sizes, int n_in,
                              void* d_out, int out_size, void* d_ws, size_t ws_size,
                              hipStream_t stream) {
  const float* Q = (const float*)d_in[0];
  const float* K = (const float*)d_in[1];
  const float* V = (const float*)d_in[2];
  float* out = (float*)d_out;

  unsigned short* kswz = (unsigned short*)d_ws;
  unsigned short* vT   = kswz + (size_t)NHEAD * SEQ * HN;

  prep_kv<<<4608, 256, 0, stream>>>(K, V, kswz, vT);
  attn_main<<<512, 256, 0, stream>>>(Q, kswz, vT, out);
}

// Round 7
// 80.736 us; speedup vs baseline: 1.1600x; 1.0582x over previous
//
#include <hip/hip_runtime.h>
#include <hip/hip_bf16.h>
#include <stdint.h>

typedef __attribute__((ext_vector_type(8))) short short8;
typedef __attribute__((ext_vector_type(8))) unsigned short ushort8;
typedef __attribute__((ext_vector_type(4))) float f32x4;
typedef __attribute__((ext_vector_type(4))) int int4v;

#define NHEAD 32
#define SEQ   2048
#define HN    128

static constexpr float INV_NORM = 0.08838834764831845f;  // 1/sqrt(128), folded into Q

__device__ __forceinline__ unsigned short f2bf(float f) {
  union { float f; unsigned u; } v; v.f = f;
  unsigned r = v.u + 0x7fffu + ((v.u >> 16) & 1u);   // RNE
  return (unsigned short)(r >> 16);
}

__device__ __forceinline__ f32x4 mfma16(short8 a, short8 b, f32x4 c) {
  return __builtin_amdgcn_mfma_f32_16x16x32_bf16(a, b, c, 0, 0, 0);
}

__device__ __forceinline__ void gl_lds16(const void* g, void* l) {
  __builtin_amdgcn_global_load_lds(
      (const __attribute__((address_space(1))) unsigned int*)g,
      (__attribute__((address_space(3))) unsigned int*)l, 16, 0, 0);
}

// ---- fused prep (unchanged, R3/R5-proven):
__global__ __launch_bounds__(256) void prep_kv(const float* __restrict__ K,
                                               const float* __restrict__ V,
                                               unsigned short* __restrict__ kswz,
                                               unsigned short* __restrict__ vT) {
  __shared__ unsigned short lds[128 * 136];
  int bid = blockIdx.x;
  int tid = threadIdx.x;
  if (bid < 4096) {
    int idx = bid * 256 + tid;     // chunk id: 32*2048*16
    int cl = idx & 15;
    int t  = (idx >> 4) & 2047;
    int bn = idx >> 15;
    const float4* src = (const float4*)(K + ((size_t)t * 32 + bn) * 128 + cl * 8);
    float4 a = src[0], b = src[1];
    ushort8 o;
    o[0]=f2bf(a.x); o[1]=f2bf(a.y); o[2]=f2bf(a.z); o[3]=f2bf(a.w);
    o[4]=f2bf(b.x); o[5]=f2bf(b.y); o[6]=f2bf(b.z); o[7]=f2bf(b.w);
    *(ushort8*)(kswz + ((size_t)bn * 2048 + t) * 128 + ((cl ^ (t & 7)) * 8)) = o;
  } else {
    int vb = bid - 4096;
    int bn = vb >> 4;
    int t0 = (vb & 15) << 7;
    int r = tid >> 1, h0 = (tid & 1) * 64;
    const float* src = V + ((size_t)(t0 + r) * 32 + bn) * 128 + h0;
#pragma unroll
    for (int j = 0; j < 8; ++j) {
      float4 a = *(const float4*)(src + j * 8);
      float4 b = *(const float4*)(src + j * 8 + 4);
      ushort8 o;
      o[0]=f2bf(a.x); o[1]=f2bf(a.y); o[2]=f2bf(a.z); o[3]=f2bf(a.w);
      o[4]=f2bf(b.x); o[5]=f2bf(b.y); o[6]=f2bf(b.z); o[7]=f2bf(b.w);
      *(ushort8*)&lds[r * 136 + h0 + j * 8] = o;
    }
    __syncthreads();
    int h = tid >> 1, ts = (tid & 1) * 64;
    unsigned short tmp[64];
#pragma unroll
    for (int j = 0; j < 64; ++j) {
      int p = j & 31;
      int tloc = ((p >> 3) & 3) * 4 + ((p >> 2) & 1) * 16 + (p & 3);
      tmp[j] = lds[(ts + (j & 32) + tloc) * 136 + h];
    }
    ushort8* dst = (ushort8*)(vT + ((size_t)bn * 128 + h) * 2048 + t0 + ts);
#pragma unroll
    for (int j = 0; j < 8; ++j) dst[j] = *(ushort8*)&tmp[j * 8];
  }
}

// ---- fragment/softmax helpers --------------------------------------------
__device__ __forceinline__ void read_kf(const char* kb, int l15, int hi,
                                        short8 (&kf)[2][4]) {
  int xr = (l15 & 7) << 4;      // rows nt*16+l15: (row&7)==(l15&7), xr invariant
#pragma unroll
  for (int nt = 0; nt < 2; ++nt) {
    const char* krow = kb + (nt * 16 + l15) * 256;
#pragma unroll
    for (int kk = 0; kk < 4; ++kk)
      kf[nt][kk] = *(const short8*)(krow + (((kk * 4 + hi) * 16) ^ xr));
  }
}

__device__ __forceinline__ void read_vf(const char* vbh, int l15, int hi,
                                        short8 (&vf)[8]) {
#pragma unroll
  for (int ht = 0; ht < 8; ++ht)
    vf[ht] = *(const short8*)(vbh + (ht * 16 + l15) * 64 +
                              ((((l15 >> 1) + hi) & 3) * 16));
}

__device__ __forceinline__ short8 packp(const float (&e)[8], float& da) {
  da += ((e[0] + e[1]) + (e[2] + e[3])) + ((e[4] + e[5]) + (e[6] + e[7]));
  unsigned w0, w1, w2, w3;
  asm("v_cvt_pk_bf16_f32 %0, %1, %2" : "=v"(w0) : "v"(e[0]), "v"(e[1]));
  asm("v_cvt_pk_bf16_f32 %0, %1, %2" : "=v"(w1) : "v"(e[2]), "v"(e[3]));
  asm("v_cvt_pk_bf16_f32 %0, %1, %2" : "=v"(w2) : "v"(e[4]), "v"(e[5]));
  asm("v_cvt_pk_bf16_f32 %0, %1, %2" : "=v"(w3) : "v"(e[6]), "v"(e[7]));
  union { int4v u; short8 s; } pk;
  pk.u = (int4v){(int)w0, (int)w1, (int)w2, (int)w3};
  return pk.s;
}

// Q pre-scaled by 1/sqrt(128): probability = exp(S) directly.
__device__ __forceinline__ short8 softp_m(const f32x4 (&sv)[2], int t0h, int qbase,
                                          int l15, int hi, float& da) {
  float e[8];
#pragma unroll
  for (int nt = 0; nt < 2; ++nt)
#pragma unroll
    for (int i = 0; i < 4; ++i) {
      float x = __expf(sv[nt][i]);
      int kv = t0h + nt * 16 + hi * 4 + i;
      e[nt * 4 + i] = (kv <= qbase + l15) ? x : 0.0f;
    }
  return packp(e, da);
}

__device__ __forceinline__ short8 softp_u(const f32x4 (&sv)[2], float& da) {
  float e[8];
#pragma unroll
  for (int nt = 0; nt < 2; ++nt)
#pragma unroll
    for (int i = 0; i < 4; ++i)
      e[nt * 4 + i] = __expf(sv[nt][i]);
  return packp(e, da);
}

// ---- main: 512 blocks x 512 threads (8 waves x 16 q-rows = 128-row
// q-tile), KVB=64 double-buffered (64KB LDS), NO kv-split, one barrier
// per 64 kv.  2 blocks/CU x 8 waves = 16 waves/CU = 4 waves/SIMD: the
// ~1000-cyc per-half-tile dependency chain (R4/R6 invariant: 1125
// cyc/wave-half-tile at 2 waves/SIMD) now has 3 other waves to overlap.
// Staging is shared by 8 waves -> L2 demand unchanged (~29 B/cyc/CU).
// Balance: qt=(z<8)?15-z:z-8 -> co-resident pair {z,z+8} sums to 34
// iterations; heavy blocks first (LPT).
// __launch_bounds__(512,2): reg cap = 256/2 = 128 (R1/R3: cap=256/w);
// per-wave state ~76 regs (R4-proven loop), no spill.
__global__ __launch_bounds__(512, 2) void attn_main(const float* __restrict__ Q,
                                                    const unsigned short* __restrict__ kswz,
                                                    const unsigned short* __restrict__ vT,
                                                    float* __restrict__ out) {
  // LDS: K 2x16KB | V 2x16KB (each V buf = two 8KB halves) = 65536
  __shared__ char smem[65536];
  int tid = threadIdx.x;
  int lane = tid & 63;
  int w = tid >> 6;                     // 0..7
  int l15 = lane & 15;
  int hi = lane >> 4;

  int bid = blockIdx.x;
  int bn = bid & 31;                    // head -> XCD bid%8 = bn%8 (stable)
  int z = bid >> 5;                     // [0,16)
  int qt = (z < 8) ? (15 - z) : (z - 8);
  int qb = qt * 128 + w * 16;           // this wave's 16 q-rows
  int ntile = 2 * qt + 2;               // 64-kv iterations

  // Q B-fragments, PRE-SCALED by 1/sqrt(128): softmax is exp(S) direct.
  short8 qf[4];
  {
    const float* qrow = Q + ((size_t)(qb + l15) * 32 + bn) * 128;
#pragma unroll
    for (int kk = 0; kk < 4; ++kk) {
      float4 a = *(const float4*)(qrow + kk * 32 + hi * 8);
      float4 b = *(const float4*)(qrow + kk * 32 + hi * 8 + 4);
      short8 o;
      o[0]=(short)f2bf(a.x*INV_NORM); o[1]=(short)f2bf(a.y*INV_NORM);
      o[2]=(short)f2bf(a.z*INV_NORM); o[3]=(short)f2bf(a.w*INV_NORM);
      o[4]=(short)f2bf(b.x*INV_NORM); o[5]=(short)f2bf(b.y*INV_NORM);
      o[6]=(short)f2bf(b.z*INV_NORM); o[7]=(short)f2bf(b.w*INV_NORM);
      qf[kk] = o;
    }
  }

  f32x4 zz = {0.f, 0.f, 0.f, 0.f};
  f32x4 acc[8];
#pragma unroll
  for (int ht = 0; ht < 8; ++ht) acc[ht] = zz;
  float dacc = 0.f;

  const char* kg = (const char*)(kswz + (size_t)bn * 2048 * 128);
  const char* vg = (const char*)(vT + (size_t)bn * 128 * 2048);

  auto stage = [&](int buf, int t0) {  // 4 gl_lds per lane (16KB K + 16KB V)
    const char* ksrc = kg + (size_t)t0 * 256;
    char* kl = smem + buf * 16384;
    int c = tid;                       // 0..511
#pragma unroll
    for (int rr = 0; rr < 2; ++rr)
      gl_lds16(ksrc + (size_t)(c + rr * 512) * 16, kl + (c + rr * 512) * 16);
    char* vl = smem + 32768 + buf * 16384;
#pragma unroll
    for (int s = 0; s < 2; ++s) {
      int h = c >> 2, sp = c & 3;
      int sl = (sp - (h >> 1)) & 3;
      gl_lds16(vg + (size_t)h * 4096 + (t0 + s * 32) * 2 + sl * 16,
               vl + s * 8192 + c * 16);
    }
  };

  // drain Q loads so in-loop vmcnt sees ONLY stage loads
  asm volatile("s_waitcnt vmcnt(0)" ::: "memory");
  stage(0, 0);

  int cur = 0;
  for (int it = 0; it < ntile; ++it) {
    int t0 = it * 64;
    asm volatile("s_waitcnt vmcnt(0)" ::: "memory");   // stage(it) landed
    __builtin_amdgcn_s_barrier();                      // all waves' stage done
    if (it + 1 < ntile) stage(cur ^ 1, t0 + 64);       // prefetch next tile

    const char* kb = smem + cur * 16384;
    const char* vb = smem + 32768 + cur * 16384;
#pragma unroll
    for (int half = 0; half < 2; ++half) {
      int t0h = t0 + half * 32;
      if (t0h <= qb + 15) {
        const char* kbh = kb + half * 8192;
        const char* vbh = vb + half * 8192;
        // K fragments
        short8 kf[2][4];
        read_kf(kbh, l15, hi, kf);
        // QK^T (swapped): lane holds S^T[kv = 4hi+i (+16nt)][q = l15]
        f32x4 sv[2] = {zz, zz};
        __builtin_amdgcn_s_setprio(1);
#pragma unroll
        for (int nt = 0; nt < 2; ++nt)
#pragma unroll
          for (int kk = 0; kk < 4; ++kk)
            sv[nt] = mfma16(kf[nt][kk], qf[kk], sv[nt]);
        __builtin_amdgcn_s_setprio(0);
        // V fragment reads; latency hides under softmax
        short8 vf[8];
        read_vf(vbh, l15, hi, vf);
        bool mask = (t0h + 31 > qb);
        short8 p = mask ? softp_m(sv, t0h, qb, l15, hi, dacc)
                        : softp_u(sv, dacc);
        // PV (V rows pre-permuted to match P k-slot order)
        __builtin_amdgcn_s_setprio(1);
#pragma unroll
        for (int ht = 0; ht < 8; ++ht)
          acc[ht] = mfma16(p, vf[ht], acc[ht]);
        __builtin_amdgcn_s_setprio(0);
      }
    }
    cur ^= 1;
  }

  // denominator: reduce partials across hi (lanes l15 + 16*hi)
  {
    float d = dacc;
    d += __shfl_xor(d, 16);
    d += __shfl_xor(d, 32);
    dacc = d;                        // function of l15 only
  }
  float* dn = out + 8388608;
  if (hi == 0) dn[(size_t)bn * 2048 + qb + l15] = dacc;

  // per-output-row inverse denominators via lane broadcast
  float inv[4];
#pragma unroll
  for (int i = 0; i < 4; ++i)
    inv[i] = __builtin_amdgcn_rcpf(__shfl(dacc, hi * 4 + i));

  // ctx: out[s*4096 + bn*128 + h]; lane holds O[q = qb+4hi+i][h = 16ht+l15]
#pragma unroll
  for (int i = 0; i < 4; ++i) {
    float* orow = out + (size_t)(qb + hi * 4 + i) * 4096 + bn * 128 + l15;
#pragma unroll
    for (int ht = 0; ht < 8; ++ht)
      orow[ht * 16] = acc[ht][i] * inv[i];
  }
}

extern "C" void kernel_launch(void* const* d_in, const int* in_sizes, int n_in,
                              void* d_out, int out_size, void* d_ws, size_t ws_size,
                              hipStream_t stream) {
  const float* Q = (const float*)d_in[0];
  const float* K = (const float*)d_in[1];
  const float* V = (const float*)d_in[2];
  float* out = (float*)d_out;

  unsigned short* kswz = (unsigned short*)d_ws;
  unsigned short* vT   = kswz + (size_t)NHEAD * SEQ * HN;

  prep_kv<<<4608, 256, 0, stream>>>(K, V, kswz, vT);
  attn_main<<<512, 512, 0, stream>>>(Q, kswz, vT, out);
}